// Round 5
// baseline (244.078 us; speedup 1.0000x reference)
//
#include <hip/hip_runtime.h>
#include <math.h>

#define N_NODE    1000000
#define N_BOND    100000
#define K_TWIST   40
#define MAX_ORDER 8
#define N_DOMAIN  10000
#define N_PER_DOM 100           // N_NODE / N_DOMAIN
#define N_GROUP   12500         // N_BOND / MAX_ORDER
#define N_TWIST   500000        // N_GROUP * K_TWIST  (nodes >= N_TWIST never twisted)
#define SIGMA_MAXF 3.14159265358979323846f

#define CBLK  512
#define CGRID ((N_GROUP + CBLK - 1) / CBLK)   // 25 blocks -> trivially co-resident

// Session lessons:
//  R5/R6: in-kernel barriers with __threadfence cost ~7 us/phase (cross-XCD
//    L2 writeback+invalidate round trips), independent of poll semantics.
//  R8 accounting: per-dispatch boundary ~5 us (from R0->R1 delta algebra);
//    12 dispatches = ~60 us of overhead -> dispatch-count is the lever.
//  R9 (this round): fenceless chain. All M data moves via RELAXED agent-scope
//    atomics (sc0 sc1: bypass non-coherent L1/L2, read/write the coherent
//    point directly). Barrier = syncthreads (drains vmcnt) + relaxed
//    fetch_add + relaxed spin. ZERO cache-maintenance instructions.
//  R7: never assume ws_size -> runtime branch (Path B = proven R0 structure).

// ws float layout (Path A):
//   rt    [0,       120000)   10000*12
//   M0    [120000,  270000)   12500*12
//   M1    [270000,  420000)   12500*12
//   sums  [420000,  570000)   10000*15
//   prep  [570000, 1770000)   100000*12, order-major: slot (o*N_GROUP+g)*12
//   ctr   [1770000, 1770008)  8 uints (barrier counters, zeroed by prep_k)
#define WS_RT    0
#define WS_M0    120000
#define WS_M1    270000
#define WS_SUMS  420000
#define WS_PREP  570000
#define WS_CTR   1770000
#define WS_FLOATS_NEEDED 1770016u

// Coherent (agent-scope, relaxed) float access: lowers to global load/store
// with sc0 sc1 — bypasses the per-XCD non-coherent caches. No fences.
__device__ __forceinline__ float ld_coh(const float* p)
{
    return __hip_atomic_load(p, __ATOMIC_RELAXED, __HIP_MEMORY_SCOPE_AGENT);
}
__device__ __forceinline__ void st_coh(float* p, float v)
{
    __hip_atomic_store(p, v, __ATOMIC_RELAXED, __HIP_MEMORY_SCOPE_AGENT);
}

// ===========================================================================
// Path A kernels
// ===========================================================================

// prep_k: one thread per bond. Hoists everything order-invariant out of the
// chain at HIGH parallelism: trig, anno decode, raw endpoint gathers,
// endpoint-group indices. Order-major so chain phase o reads coalesced.
//   [0]=c [1]=s [2..4]=pos[u] [5..7]=pos[v] [8]=gu [9]=gv [10]=ok [11]=pad
// Thread 0 also zeroes the barrier counters (ws is poisoned each iteration);
// the dispatch boundary publishes them to chain_k.
__global__ __launch_bounds__(256) void prep_k(
    const float* __restrict__ pos, const float* __restrict__ info_level,
    const int* __restrict__ anno, const float* __restrict__ eps,
    const float* __restrict__ uni, const int* __restrict__ from_prior_p,
    float* __restrict__ prep, unsigned int* __restrict__ ctr)
{
    int b = blockIdx.x * 256 + threadIdx.x;
    if (b == 0) {
        #pragma unroll
        for (int k = 0; k < 8; k++) ctr[k] = 0u;
    }
    if (b >= N_BOND) return;
    int ord = anno[3*b];
    int u   = anno[3*b + 1];
    int v   = anno[3*b + 2];
    float info = info_level[b];
    float ang  = eps[b] * (1.0f - info) * SIGMA_MAXF;
    if (from_prior_p[0] != 0 && info == 0.0f) ang = uni[b];
    int o = b % MAX_ORDER;          // slot read by chain phase o
    int g = b / MAX_ORDER;
    float* pr = prep + (size_t)(o * N_GROUP + g) * 12;
    pr[0] = cosf(ang);
    pr[1] = sinf(ang);
    pr[2] = pos[3*u+0]; pr[3] = pos[3*u+1]; pr[4] = pos[3*u+2];
    pr[5] = pos[3*v+0]; pr[6] = pos[3*v+1]; pr[7] = pos[3*v+2];
    int gu = (u < N_TWIST) ? (u / K_TWIST) : -1;
    int gv = (v < N_TWIST) ? (v / K_TWIST) : -1;
    ((int*)pr)[8]  = gu;
    ((int*)pr)[9]  = gv;
    ((int*)pr)[10] = (ord == o) ? 1 : 0;
    pr[11] = 0.f;
}

// chain_k: ALL 8 orders, ONE dispatch, fenceless barriers. M data moves only
// through coherent (sc0 sc1) accesses, so the inter-phase barrier needs no
// cache maintenance: syncthreads (compiler drains vmcnt -> M stores are at
// the coherent point) + relaxed arrive + relaxed spin + syncthreads.
// Math identical to the verified compose chain (absmax 0.5).
__global__ __launch_bounds__(CBLK) void chain_k(
    const float* __restrict__ prep,
    float* __restrict__ M0, float* __restrict__ M1,
    unsigned int* __restrict__ ctr)
{
    int g = blockIdx.x * CBLK + threadIdx.x;
    bool active = (g < N_GROUP);

    #pragma unroll
    for (int o = 0; o < MAX_ORDER; o++) {
        float* Mp = (o & 1) ? M0 : M1;
        float* Mc = (o & 1) ? M1 : M0;
        if (active) {
            const float4* pr4 =
                (const float4*)(prep + (size_t)(o * N_GROUP + g) * 12);
            float4 f0 = pr4[0], f1 = pr4[1], f2 = pr4[2];
            float c = f0.x, s = f0.y;
            float pu0 = f0.z, pu1 = f0.w, pu2 = f1.x;
            float pv0 = f1.y, pv1 = f1.z, pv2 = f1.w;
            int gu = __float_as_int(f2.x);
            int gv = __float_as_int(f2.y);
            int ok = __float_as_int(f2.z);
            float* mg = Mc + 12 * g;
            if (!ok) {                               // safety fallback
                if (o == 0) {
                    st_coh(mg+0,1.f); st_coh(mg+1,0.f); st_coh(mg+2,0.f);
                    st_coh(mg+3,0.f); st_coh(mg+4,1.f); st_coh(mg+5,0.f);
                    st_coh(mg+6,0.f); st_coh(mg+7,0.f); st_coh(mg+8,1.f);
                    st_coh(mg+9,0.f); st_coh(mg+10,0.f); st_coh(mg+11,0.f);
                } else {
                    const float* mp = Mp + 12 * g;
                    #pragma unroll
                    for (int k = 0; k < 12; k++) st_coh(mg+k, ld_coh(mp+k));
                }
            } else {
                if (o > 0) {
                    if (gu >= 0) {
                        const float* m = Mp + 12 * gu;
                        float m0=ld_coh(m+0),m1=ld_coh(m+1),m2=ld_coh(m+2);
                        float m3=ld_coh(m+3),m4=ld_coh(m+4),m5=ld_coh(m+5);
                        float m6=ld_coh(m+6),m7=ld_coh(m+7),m8=ld_coh(m+8);
                        float m9=ld_coh(m+9),mA=ld_coh(m+10),mB=ld_coh(m+11);
                        float a = m0*pu0 + m1*pu1 + m2*pu2 + m9;
                        float d = m3*pu0 + m4*pu1 + m5*pu2 + mA;
                        float e = m6*pu0 + m7*pu1 + m8*pu2 + mB;
                        pu0 = a; pu1 = d; pu2 = e;
                    }
                    if (gv >= 0) {
                        const float* m = Mp + 12 * gv;
                        float m0=ld_coh(m+0),m1=ld_coh(m+1),m2=ld_coh(m+2);
                        float m3=ld_coh(m+3),m4=ld_coh(m+4),m5=ld_coh(m+5);
                        float m6=ld_coh(m+6),m7=ld_coh(m+7),m8=ld_coh(m+8);
                        float m9=ld_coh(m+9),mA=ld_coh(m+10),mB=ld_coh(m+11);
                        float a = m0*pv0 + m1*pv1 + m2*pv2 + m9;
                        float d = m3*pv0 + m4*pv1 + m5*pv2 + mA;
                        float e = m6*pv0 + m7*pv1 + m8*pv2 + mB;
                        pv0 = a; pv1 = d; pv2 = e;
                    }
                }
                float ax = pv0-pu0, ay = pv1-pu1, az = pv2-pu2;
                float inv = 1.0f / (sqrtf(ax*ax + ay*ay + az*az) + 1e-12f);
                ax *= inv; ay *= inv; az *= inv;
                float t = 1.0f - c;
                float R00 = c + t*ax*ax,     R01 = -s*az + t*ax*ay, R02 =  s*ay + t*ax*az;
                float R10 =  s*az + t*ay*ax, R11 = c + t*ay*ay,     R12 = -s*ax + t*ay*az;
                float R20 = -s*ay + t*az*ax, R21 =  s*ax + t*az*ay, R22 = c + t*az*az;
                if (o == 0) {
                    st_coh(mg+0,R00); st_coh(mg+1,R01); st_coh(mg+2,R02);
                    st_coh(mg+3,R10); st_coh(mg+4,R11); st_coh(mg+5,R12);
                    st_coh(mg+6,R20); st_coh(mg+7,R21); st_coh(mg+8,R22);
                    st_coh(mg+9,  pv0 - (R00*pv0 + R01*pv1 + R02*pv2));
                    st_coh(mg+10, pv1 - (R10*pv0 + R11*pv1 + R12*pv2));
                    st_coh(mg+11, pv2 - (R20*pv0 + R21*pv1 + R22*pv2));
                } else {
                    const float* mp = Mp + 12 * g;
                    float m0=ld_coh(mp+0),m1=ld_coh(mp+1),m2=ld_coh(mp+2);
                    float m3=ld_coh(mp+3),m4=ld_coh(mp+4),m5=ld_coh(mp+5);
                    float m6=ld_coh(mp+6),m7=ld_coh(mp+7),m8=ld_coh(mp+8);
                    float m9=ld_coh(mp+9),mA=ld_coh(mp+10),mB=ld_coh(mp+11);
                    st_coh(mg+0, R00*m0 + R01*m3 + R02*m6);
                    st_coh(mg+1, R00*m1 + R01*m4 + R02*m7);
                    st_coh(mg+2, R00*m2 + R01*m5 + R02*m8);
                    st_coh(mg+3, R10*m0 + R11*m3 + R12*m6);
                    st_coh(mg+4, R10*m1 + R11*m4 + R12*m7);
                    st_coh(mg+5, R10*m2 + R11*m5 + R12*m8);
                    st_coh(mg+6, R20*m0 + R21*m3 + R22*m6);
                    st_coh(mg+7, R20*m1 + R21*m4 + R22*m7);
                    st_coh(mg+8, R20*m2 + R21*m5 + R22*m8);
                    float d0 = m9-pv0, d1 = mA-pv1, d2 = mB-pv2;
                    st_coh(mg+9,  R00*d0 + R01*d1 + R02*d2 + pv0);
                    st_coh(mg+10, R10*d0 + R11*d1 + R12*d2 + pv1);
                    st_coh(mg+11, R20*d0 + R21*d1 + R22*d2 + pv2);
                }
            }
        }
        if (o < MAX_ORDER - 1) {
            // Fenceless device barrier: syncthreads drains each wave's vmcnt
            // (sc0sc1 stores are then AT the coherent point), so arrival
            // needs no release fence; readers use ld_coh, so exit needs no
            // invalidate.
            __syncthreads();
            if (threadIdx.x == 0) {
                __hip_atomic_fetch_add(&ctr[o], 1u, __ATOMIC_RELAXED,
                                       __HIP_MEMORY_SCOPE_AGENT);
                long guard = 0;
                while (__hip_atomic_load(&ctr[o], __ATOMIC_RELAXED,
                                         __HIP_MEMORY_SCOPE_AGENT)
                       < (unsigned)gridDim.x) {
                    __builtin_amdgcn_s_sleep(4);
                    if (++guard > (1L << 22)) break;  // ~0.5s guard; wrong
                }                                     // results beat a hang
            }
            __syncthreads();
        }
    }
}

// apply_k (Path A): ONE fused kernel over all nodes (scratch in ws, no
// aliasing with out). Mf was written sc0sc1 by chain_k; the dispatch
// boundary makes plain cached reads safe here.
__global__ void apply_k(const float* __restrict__ pos,
                        const float* __restrict__ Mf,
                        const float* __restrict__ rt,
                        float* __restrict__ out)
{
    int n = blockIdx.x * 256 + threadIdx.x;
    if (n >= N_NODE) return;
    const float* w = rt + 12 * (n / N_PER_DOM);
    float q0 = pos[3*n+0], q1 = pos[3*n+1], q2 = pos[3*n+2];
    float p0 = q0, p1 = q1, p2 = q2;
    if (n < N_TWIST) {
        const float* m = Mf + 12 * (n / K_TWIST);
        p0 = m[0]*q0 + m[1]*q1 + m[2]*q2 + m[9];
        p1 = m[3]*q0 + m[4]*q1 + m[5]*q2 + m[10];
        p2 = m[6]*q0 + m[7]*q1 + m[8]*q2 + m[11];
    }
    out[3*n+0] = w[0]*p0 + w[1]*p1 + w[2]*p2 + w[9];
    out[3*n+1] = w[3]*p0 + w[4]*p1 + w[5]*p2 + w[10];
    out[3*n+2] = w[6]*p0 + w[7]*p1 + w[8]*p2 + w[11];
}

// ===========================================================================
// Path B kernels — proven R0 baseline structure (scratch in out-high)
// ===========================================================================

__global__ __launch_bounds__(256) void compose_legacy_k(
    const float* __restrict__ pos, const float* __restrict__ info_level,
    const int* __restrict__ anno, const float* __restrict__ eps,
    const float* __restrict__ uni, const int* __restrict__ from_prior_p,
    const float* __restrict__ Mp, float* __restrict__ Mc, int o)
{
    int g = blockIdx.x * 256 + threadIdx.x;
    if (g >= N_GROUP) return;
    int b = g * MAX_ORDER + o;
    float* mg = Mc + 12 * g;
    if (anno[3*b] != o) {                       // safety fallback
        if (o == 0) {
            mg[0]=1.f; mg[1]=0.f; mg[2]=0.f;
            mg[3]=0.f; mg[4]=1.f; mg[5]=0.f;
            mg[6]=0.f; mg[7]=0.f; mg[8]=1.f;
            mg[9]=0.f; mg[10]=0.f; mg[11]=0.f;
        } else {
            const float* mp = Mp + 12 * g;
            #pragma unroll
            for (int k = 0; k < 12; k++) mg[k] = mp[k];
        }
        return;
    }
    int u = anno[3*b + 1];
    int v = anno[3*b + 2];
    float pu0 = pos[3*u+0], pu1 = pos[3*u+1], pu2 = pos[3*u+2];
    float pv0 = pos[3*v+0], pv1 = pos[3*v+1], pv2 = pos[3*v+2];
    if (o > 0) {
        if (u < N_TWIST) {
            const float* m = Mp + 12 * (u / K_TWIST);
            float a = m[0]*pu0 + m[1]*pu1 + m[2]*pu2 + m[9];
            float c = m[3]*pu0 + m[4]*pu1 + m[5]*pu2 + m[10];
            float e = m[6]*pu0 + m[7]*pu1 + m[8]*pu2 + m[11];
            pu0 = a; pu1 = c; pu2 = e;
        }
        if (v < N_TWIST) {
            const float* m = Mp + 12 * (v / K_TWIST);
            float a = m[0]*pv0 + m[1]*pv1 + m[2]*pv2 + m[9];
            float c = m[3]*pv0 + m[4]*pv1 + m[5]*pv2 + m[10];
            float e = m[6]*pv0 + m[7]*pv1 + m[8]*pv2 + m[11];
            pv0 = a; pv1 = c; pv2 = e;
        }
    }
    float info = info_level[b];
    float ang  = eps[b] * (1.0f - info) * SIGMA_MAXF;
    if (from_prior_p[0] != 0 && info == 0.0f) ang = uni[b];
    float ax = pv0-pu0, ay = pv1-pu1, az = pv2-pu2;
    float inv = 1.0f / (sqrtf(ax*ax + ay*ay + az*az) + 1e-12f);
    ax *= inv; ay *= inv; az *= inv;
    float c = cosf(ang), s = sinf(ang), t = 1.0f - c;
    float R00 = c + t*ax*ax,     R01 = -s*az + t*ax*ay, R02 =  s*ay + t*ax*az;
    float R10 =  s*az + t*ay*ax, R11 = c + t*ay*ay,     R12 = -s*ax + t*ay*az;
    float R20 = -s*ay + t*az*ax, R21 =  s*ax + t*az*ay, R22 = c + t*az*az;
    if (o == 0) {
        mg[0]=R00; mg[1]=R01; mg[2]=R02;
        mg[3]=R10; mg[4]=R11; mg[5]=R12;
        mg[6]=R20; mg[7]=R21; mg[8]=R22;
        mg[9]  = pv0 - (R00*pv0 + R01*pv1 + R02*pv2);
        mg[10] = pv1 - (R10*pv0 + R11*pv1 + R12*pv2);
        mg[11] = pv2 - (R20*pv0 + R21*pv1 + R22*pv2);
    } else {
        const float* mp = Mp + 12 * g;
        mg[0] = R00*mp[0] + R01*mp[3] + R02*mp[6];
        mg[1] = R00*mp[1] + R01*mp[4] + R02*mp[7];
        mg[2] = R00*mp[2] + R01*mp[5] + R02*mp[8];
        mg[3] = R10*mp[0] + R11*mp[3] + R12*mp[6];
        mg[4] = R10*mp[1] + R11*mp[4] + R12*mp[7];
        mg[5] = R10*mp[2] + R11*mp[5] + R12*mp[8];
        mg[6] = R20*mp[0] + R21*mp[3] + R22*mp[6];
        mg[7] = R20*mp[1] + R21*mp[4] + R22*mp[7];
        mg[8] = R20*mp[2] + R21*mp[5] + R22*mp[8];
        float d0 = mp[9]-pv0, d1 = mp[10]-pv1, d2 = mp[11]-pv2;
        mg[9]  = R00*d0 + R01*d1 + R02*d2 + pv0;
        mg[10] = R10*d0 + R11*d1 + R12*d2 + pv1;
        mg[11] = R20*d0 + R21*d1 + R22*d2 + pv2;
    }
}

__global__ void apply_low_k(const float* __restrict__ pos,
                            const float* __restrict__ Mf,
                            const float* __restrict__ rt,
                            float* __restrict__ out)
{
    int n = blockIdx.x * 256 + threadIdx.x;
    if (n >= N_TWIST) return;
    const float* m = Mf + 12 * (n / K_TWIST);
    const float* w = rt + 12 * (n / N_PER_DOM);
    float q0 = pos[3*n+0], q1 = pos[3*n+1], q2 = pos[3*n+2];
    float p0 = m[0]*q0 + m[1]*q1 + m[2]*q2 + m[9];
    float p1 = m[3]*q0 + m[4]*q1 + m[5]*q2 + m[10];
    float p2 = m[6]*q0 + m[7]*q1 + m[8]*q2 + m[11];
    out[3*n+0] = w[0]*p0 + w[1]*p1 + w[2]*p2 + w[9];
    out[3*n+1] = w[3]*p0 + w[4]*p1 + w[5]*p2 + w[10];
    out[3*n+2] = w[6]*p0 + w[7]*p1 + w[8]*p2 + w[11];
}

__global__ void apply_high_k(const float* __restrict__ pos,
                             const float* __restrict__ rt,
                             float* __restrict__ out)
{
    int i = blockIdx.x * 256 + threadIdx.x;
    int n = N_TWIST + i;
    if (n >= N_NODE) return;
    const float* w = rt + 12 * (n / N_PER_DOM);
    float q0 = pos[3*n+0], q1 = pos[3*n+1], q2 = pos[3*n+2];
    out[3*n+0] = w[0]*q0 + w[1]*q1 + w[2]*q2 + w[9];
    out[3*n+1] = w[3]*q0 + w[4]*q1 + w[5]*q2 + w[10];
    out[3*n+2] = w[6]*q0 + w[7]*q1 + w[8]*q2 + w[11];
}

// ===========================================================================
// Shared kernels (both paths)
// ===========================================================================

__global__ __launch_bounds__(256) void reduce_k(const float* __restrict__ pos,
                                                const float* __restrict__ Mf,
                                                float* __restrict__ sums)
{
    int wave = threadIdx.x >> 6;
    int lane = threadIdx.x & 63;
    int d = blockIdx.x * 4 + wave;          // grid = 2500 -> d in [0,10000)
    float a[15];
    #pragma unroll
    for (int k = 0; k < 15; k++) a[k] = 0.f;
    for (int i = lane; i < N_PER_DOM; i += 64) {
        int n = d * N_PER_DOM + i;
        float q0 = pos[3*n+0], q1 = pos[3*n+1], q2 = pos[3*n+2];
        float p0 = q0, p1 = q1, p2 = q2;
        if (n < N_TWIST) {
            const float* m = Mf + 12 * (n / K_TWIST);
            p0 = m[0]*q0 + m[1]*q1 + m[2]*q2 + m[9];
            p1 = m[3]*q0 + m[4]*q1 + m[5]*q2 + m[10];
            p2 = m[6]*q0 + m[7]*q1 + m[8]*q2 + m[11];
        }
        a[0]+=p0;    a[1]+=p1;    a[2]+=p2;
        a[3]+=q0;    a[4]+=q1;    a[5]+=q2;
        a[6]+=p0*q0; a[7]+=p0*q1; a[8]+=p0*q2;
        a[9]+=p1*q0; a[10]+=p1*q1;a[11]+=p1*q2;
        a[12]+=p2*q0;a[13]+=p2*q1;a[14]+=p2*q2;
    }
    #pragma unroll
    for (int off = 32; off > 0; off >>= 1)
        #pragma unroll
        for (int k = 0; k < 15; k++) a[k] += __shfl_down(a[k], off);
    if (lane == 0) {
        float* sd = sums + (size_t)d * 15;
        #pragma unroll
        for (int k = 0; k < 15; k++) sd[k] = a[k];
    }
}

__device__ inline void cross3d(const double a[3], const double b[3], double r[3])
{
    r[0] = a[1]*b[2] - a[2]*b[1];
    r[1] = a[2]*b[0] - a[0]*b[2];
    r[2] = a[0]*b[1] - a[1]*b[0];
}

__device__ void kabsch_from_sums(const float* s, float* __restrict__ rt)
{
    const double inv_n = 1.0 / (double)N_PER_DOM;
    double sP[3] = { s[0], s[1], s[2] };
    double sQ[3] = { s[3], s[4], s[5] };
    double H[3][3];
    #pragma unroll
    for (int i = 0; i < 3; i++)
        #pragma unroll
        for (int j = 0; j < 3; j++)
            H[i][j] = (double)s[6 + 3*i + j] - sP[i]*sQ[j]*inv_n;
    double A[3][3];
    #pragma unroll
    for (int i = 0; i < 3; i++)
        #pragma unroll
        for (int j = 0; j < 3; j++)
            A[i][j] = H[0][i]*H[0][j] + H[1][i]*H[1][j] + H[2][i]*H[2][j];
    double V[3][3] = {{1,0,0},{0,1,0},{0,0,1}};
    for (int sweep = 0; sweep < 30; sweep++) {
        double off = A[0][1]*A[0][1] + A[0][2]*A[0][2] + A[1][2]*A[1][2];
        double n2  = A[0][0]*A[0][0] + A[1][1]*A[1][1] + A[2][2]*A[2][2];
        if (off <= 1e-28 * n2) break;
        for (int pp = 0; pp < 3; pp++) {
            int p = (pp == 2) ? 1 : 0;
            int q = (pp == 0) ? 1 : 2;
            double apq = A[p][q];
            if (apq == 0.0) continue;
            double tau = (A[q][q] - A[p][p]) / (2.0 * apq);
            double tj  = (tau >= 0.0 ? 1.0 : -1.0) / (fabs(tau) + sqrt(1.0 + tau*tau));
            double cj  = 1.0 / sqrt(1.0 + tj*tj);
            double sj  = tj * cj;
            int r = 3 - p - q;
            double app = A[p][p], aqq = A[q][q];
            A[p][p] = app - tj*apq;
            A[q][q] = aqq + tj*apq;
            A[p][q] = 0.0; A[q][p] = 0.0;
            double arp = A[r][p], arq = A[r][q];
            A[r][p] = cj*arp - sj*arq; A[p][r] = A[r][p];
            A[r][q] = sj*arp + cj*arq; A[q][r] = A[r][q];
            #pragma unroll
            for (int k = 0; k < 3; k++) {
                double vp = V[k][p], vq = V[k][q];
                V[k][p] = cj*vp - sj*vq;
                V[k][q] = sj*vp + cj*vq;
            }
        }
    }
    double wv[3] = { A[0][0], A[1][1], A[2][2] };
    int i0 = 0, i1 = 1, i2 = 2;
    if (wv[i0] < wv[i1]) { int t = i0; i0 = i1; i1 = t; }
    if (wv[i0] < wv[i2]) { int t = i0; i0 = i2; i2 = t; }
    if (wv[i1] < wv[i2]) { int t = i1; i1 = i2; i2 = t; }
    double v0[3] = { V[0][i0], V[1][i0], V[2][i0] };
    double v1[3] = { V[0][i1], V[1][i1], V[2][i1] };
    double v2[3] = { V[0][i2], V[1][i2], V[2][i2] };
    double s0 = sqrt(fmax(wv[i0], 0.0));
    double Rg[3][3];
    if (s0 < 1e-200) {
        Rg[0][0]=1; Rg[0][1]=0; Rg[0][2]=0;
        Rg[1][0]=0; Rg[1][1]=1; Rg[1][2]=0;
        Rg[2][0]=0; Rg[2][1]=0; Rg[2][2]=1;
    } else {
        double u0[3], u1[3], u2[3];
        #pragma unroll
        for (int i = 0; i < 3; i++)
            u0[i] = H[i][0]*v0[0] + H[i][1]*v0[1] + H[i][2]*v0[2];
        double n0 = sqrt(u0[0]*u0[0] + u0[1]*u0[1] + u0[2]*u0[2]);
        if (n0 > 0.0) { u0[0]/=n0; u0[1]/=n0; u0[2]/=n0; }
        else { u0[0]=1; u0[1]=0; u0[2]=0; }
        #pragma unroll
        for (int i = 0; i < 3; i++)
            u1[i] = H[i][0]*v1[0] + H[i][1]*v1[1] + H[i][2]*v1[2];
        double dp = u0[0]*u1[0] + u0[1]*u1[1] + u0[2]*u1[2];
        u1[0] -= dp*u0[0]; u1[1] -= dp*u0[1]; u1[2] -= dp*u0[2];
        double n1 = sqrt(u1[0]*u1[0] + u1[1]*u1[1] + u1[2]*u1[2]);
        if (n1 > 1e-12 * n0) { u1[0]/=n1; u1[1]/=n1; u1[2]/=n1; }
        else {
            double tv[3] = { (fabs(u0[0]) < 0.9) ? 1.0 : 0.0,
                             (fabs(u0[0]) < 0.9) ? 0.0 : 1.0, 0.0 };
            cross3d(u0, tv, u1);
            double nn = sqrt(u1[0]*u1[0] + u1[1]*u1[1] + u1[2]*u1[2]);
            u1[0]/=nn; u1[1]/=nn; u1[2]/=nn;
        }
        cross3d(u0, u1, u2);                    // det(U) = +1
        double c12[3]; cross3d(v1, v2, c12);
        double detV = v0[0]*c12[0] + v0[1]*c12[1] + v0[2]*c12[2];
        double dsg = (detV >= 0.0) ? 1.0 : -1.0;
        #pragma unroll
        for (int r = 0; r < 3; r++)
            #pragma unroll
            for (int c = 0; c < 3; c++)
                Rg[r][c] = v0[r]*u0[c] + v1[r]*u1[c] + dsg*v2[r]*u2[c];
    }
    double cP[3] = { sP[0]*inv_n, sP[1]*inv_n, sP[2]*inv_n };
    double cQ[3] = { sQ[0]*inv_n, sQ[1]*inv_n, sQ[2]*inv_n };
    #pragma unroll
    for (int i = 0; i < 3; i++) {
        rt[3*i+0] = (float)Rg[i][0];
        rt[3*i+1] = (float)Rg[i][1];
        rt[3*i+2] = (float)Rg[i][2];
        rt[9+i] = (float)(cQ[i] - (Rg[i][0]*cP[0] + Rg[i][1]*cP[1] + Rg[i][2]*cP[2]));
    }
}

__global__ __launch_bounds__(128) void svd_k(const float* __restrict__ sums,
                                             float* __restrict__ rt)
{
    int d = blockIdx.x * 128 + threadIdx.x;
    if (d >= N_DOMAIN) return;
    kabsch_from_sums(sums + (size_t)d * 15, rt + (size_t)d * 12);
}

// ---------------------------------------------------------------------------
extern "C" void kernel_launch(void* const* d_in, const int* in_sizes, int n_in,
                              void* d_out, int out_size, void* d_ws, size_t ws_size,
                              hipStream_t stream)
{
    const float* pos        = (const float*)d_in[0];
    const float* info_level = (const float*)d_in[1];
    const int*   anno       = (const int*)  d_in[2];
    const float* eps        = (const float*)d_in[6];
    const float* uni        = (const float*)d_in[7];
    const int*   from_prior = (const int*)  d_in[8];
    float* out = (float*)d_out;
    float* ws  = (float*)d_ws;

    if (ws_size >= (size_t)WS_FLOATS_NEEDED * sizeof(float)) {
        // ---------------- Path A: 5 dispatches total ----------------
        float* rt   = ws + WS_RT;
        float* M0   = ws + WS_M0;
        float* M1   = ws + WS_M1;
        float* sums = ws + WS_SUMS;
        float* prep = ws + WS_PREP;
        unsigned int* ctr = (unsigned int*)(ws + WS_CTR);

        prep_k<<<(N_BOND + 255)/256, 256, 0, stream>>>(
            pos, info_level, anno, eps, uni, from_prior, prep, ctr);

        // ONE dispatch for the whole 8-order chain (fenceless barriers).
        chain_k<<<CGRID, CBLK, 0, stream>>>(prep, M0, M1, ctr);
        float* Mf = M1;                      // o=7 lands in M1

        reduce_k<<<N_DOMAIN / 4, 256, 0, stream>>>(pos, Mf, sums);
        svd_k<<<(N_DOMAIN + 127)/128, 128, 0, stream>>>(sums, rt);
        apply_k<<<(N_NODE + 255)/256, 256, 0, stream>>>(pos, Mf, rt, out);
    } else {
        // ---------------- Path B: proven R0 layout (scratch in out-high) ---
        float* rt   = ws;                                 // 480 KB proven safe
        float* M0   = out + (size_t)3 * N_TWIST;          // 150,000 floats
        float* M1   = M0 + 12 * N_GROUP;                  // 150,000 floats
        float* sums = M1 + 12 * N_GROUP;                  // 150,000 floats

        for (int o = 0; o < MAX_ORDER; o++) {
            const float* Mp = (o & 1) ? M0 : M1;
            float*       Mc = (o & 1) ? M1 : M0;
            compose_legacy_k<<<(N_GROUP + 255)/256, 256, 0, stream>>>(
                pos, info_level, anno, eps, uni, from_prior, Mp, Mc, o);
        }
        float* Mf = M1;

        reduce_k<<<N_DOMAIN / 4, 256, 0, stream>>>(pos, Mf, sums);
        svd_k<<<(N_DOMAIN + 127)/128, 128, 0, stream>>>(sums, rt);
        apply_low_k<<<(N_TWIST + 255)/256, 256, 0, stream>>>(pos, Mf, rt, out);
        apply_high_k<<<(N_NODE - N_TWIST + 255)/256, 256, 0, stream>>>(pos, rt, out);
    }
}

// Round 6
// 155.061 us; speedup vs baseline: 1.5741x; 1.5741x over previous
//
#include <hip/hip_runtime.h>
#include <math.h>

#define N_NODE    1000000
#define N_BOND    100000
#define K_TWIST   40
#define MAX_ORDER 8
#define N_DOMAIN  10000
#define N_PER_DOM 100           // N_NODE / N_DOMAIN
#define N_GROUP   12500         // N_BOND / MAX_ORDER
#define N_TWIST   500000        // N_GROUP * K_TWIST  (nodes >= N_TWIST never twisted)
#define SIGMA_MAXF 3.14159265358979323846f

// Session lessons (measured):
//  R5/R6: in-kernel device barriers with __threadfence ~7 us/phase (cross-XCD
//    L2 wb+inv round trips), independent of poll semantics.
//  R9:    fenceless sc0sc1 data path is WORSE (~15 us/phase): write-through
//    stores at line granularity (WRITE_SIZE 5.3->37.5 MB) + unvectorizable
//    uncached scalar loads. Stream dispatch boundary (~3.5-5 us) is the
//    cheapest device-wide barrier on MI355X. 8-dispatch chain is final.
//  R7:    never assume ws_size -> runtime branch (Path B = proven baseline).
//  R10 (this round): merge the two INDEPENDENT kernels (prep, compose o=0)
//    into one block-partitioned dispatch (-1 boundary, c0 exec hidden);
//    vectorize apply 4 nodes/thread via float4 (4|40 and 4|100 -> no
//    group/domain straddle).

// ws float layout (Path A):
//   rt    [0,       120000)   10000*12
//   M0    [120000,  270000)   12500*12
//   M1    [270000,  420000)   12500*12
//   sums  [420000,  570000)   10000*15
//   prep  [570000, 1770000)   100000*12, order-major: slot (o*N_GROUP+g)*12
#define WS_RT    0
#define WS_M0    120000
#define WS_M1    270000
#define WS_SUMS  420000
#define WS_PREP  570000
#define WS_FLOATS_NEEDED 1770000u

#define C0_BLOCKS   ((N_GROUP + 255) / 256)          // 49
#define PREP_BLOCKS ((N_BOND + 255) / 256)           // 391
#define FUSED_BLOCKS (C0_BLOCKS + PREP_BLOCKS)       // 440

// ===========================================================================
// Path A kernels
// ===========================================================================

// fused_prep_c0_k: block-partitioned. Blocks [0,49) run compose order 0
// (reads ONLY raw inputs — independent of prep). Blocks [49,440) run prep
// for the chain (slots o>=1; o=0 slots are never read and are skipped).
// prep slot layout: [0]=c [1]=s [2..4]=pos[u] [5..7]=pos[v] [8]=gu [9]=gv
//                   [10]=ok [11]=pad   (order-major: (o*N_GROUP+g)*12)
__global__ __launch_bounds__(256) void fused_prep_c0_k(
    const float* __restrict__ pos, const float* __restrict__ info_level,
    const int* __restrict__ anno, const float* __restrict__ eps,
    const float* __restrict__ uni, const int* __restrict__ from_prior_p,
    float* __restrict__ prep, float* __restrict__ M0)
{
    if (blockIdx.x < C0_BLOCKS) {
        // ---- compose order 0 ----
        int g = blockIdx.x * 256 + threadIdx.x;
        if (g >= N_GROUP) return;
        int b = g * MAX_ORDER;              // o = 0
        float* mg = M0 + 12 * g;
        if (anno[3*b] != 0) {               // safety fallback: identity
            mg[0]=1.f; mg[1]=0.f; mg[2]=0.f;
            mg[3]=0.f; mg[4]=1.f; mg[5]=0.f;
            mg[6]=0.f; mg[7]=0.f; mg[8]=1.f;
            mg[9]=0.f; mg[10]=0.f; mg[11]=0.f;
            return;
        }
        int u = anno[3*b + 1];
        int v = anno[3*b + 2];
        float pu0 = pos[3*u+0], pu1 = pos[3*u+1], pu2 = pos[3*u+2];
        float pv0 = pos[3*v+0], pv1 = pos[3*v+1], pv2 = pos[3*v+2];
        float info = info_level[b];
        float ang  = eps[b] * (1.0f - info) * SIGMA_MAXF;
        if (from_prior_p[0] != 0 && info == 0.0f) ang = uni[b];
        float ax = pv0-pu0, ay = pv1-pu1, az = pv2-pu2;
        float inv = 1.0f / (sqrtf(ax*ax + ay*ay + az*az) + 1e-12f);
        ax *= inv; ay *= inv; az *= inv;
        float c = cosf(ang), s = sinf(ang), t = 1.0f - c;
        float R00 = c + t*ax*ax,     R01 = -s*az + t*ax*ay, R02 =  s*ay + t*ax*az;
        float R10 =  s*az + t*ay*ax, R11 = c + t*ay*ay,     R12 = -s*ax + t*ay*az;
        float R20 = -s*ay + t*az*ax, R21 =  s*ax + t*az*ay, R22 = c + t*az*az;
        mg[0]=R00; mg[1]=R01; mg[2]=R02;
        mg[3]=R10; mg[4]=R11; mg[5]=R12;
        mg[6]=R20; mg[7]=R21; mg[8]=R22;
        mg[9]  = pv0 - (R00*pv0 + R01*pv1 + R02*pv2);
        mg[10] = pv1 - (R10*pv0 + R11*pv1 + R12*pv2);
        mg[11] = pv2 - (R20*pv0 + R21*pv1 + R22*pv2);
    } else {
        // ---- prep for chain orders 1..7 ----
        int b = (blockIdx.x - C0_BLOCKS) * 256 + threadIdx.x;
        if (b >= N_BOND) return;
        int o = b % MAX_ORDER;
        if (o == 0) return;                 // o=0 slots never read
        int ord = anno[3*b];
        int u   = anno[3*b + 1];
        int v   = anno[3*b + 2];
        float info = info_level[b];
        float ang  = eps[b] * (1.0f - info) * SIGMA_MAXF;
        if (from_prior_p[0] != 0 && info == 0.0f) ang = uni[b];
        int g = b / MAX_ORDER;
        float* pr = prep + (size_t)(o * N_GROUP + g) * 12;
        pr[0] = cosf(ang);
        pr[1] = sinf(ang);
        pr[2] = pos[3*u+0]; pr[3] = pos[3*u+1]; pr[4] = pos[3*u+2];
        pr[5] = pos[3*v+0]; pr[6] = pos[3*v+1]; pr[7] = pos[3*v+2];
        int gu = (u < N_TWIST) ? (u / K_TWIST) : -1;
        int gv = (v < N_TWIST) ? (v / K_TWIST) : -1;
        ((int*)pr)[8]  = gu;
        ((int*)pr)[9]  = gv;
        ((int*)pr)[10] = (ord == o) ? 1 : 0;
        pr[11] = 0.f;
    }
}

// compose_k (o = 1..7): one thread per group, one dispatch per order (the
// dispatch boundary IS the device-wide barrier). Coalesced 48 B prep read ->
// cached Mp gathers -> ~60 VALU -> 48 B store. Math identical to verified.
__global__ __launch_bounds__(256) void compose_k(
    const float* __restrict__ prep,
    const float* __restrict__ Mp, float* __restrict__ Mc, int o)
{
    int g = blockIdx.x * 256 + threadIdx.x;
    if (g >= N_GROUP) return;
    const float4* pr4 = (const float4*)(prep + (size_t)(o * N_GROUP + g) * 12);
    float4 f0 = pr4[0], f1 = pr4[1], f2 = pr4[2];
    float c = f0.x, s = f0.y;
    float pu0 = f0.z, pu1 = f0.w, pu2 = f1.x;
    float pv0 = f1.y, pv1 = f1.z, pv2 = f1.w;
    int gu = __float_as_int(f2.x);
    int gv = __float_as_int(f2.y);
    int ok = __float_as_int(f2.z);
    float* mg = Mc + 12 * g;
    if (!ok) {                                   // safety fallback: carry
        const float* mp = Mp + 12 * g;
        #pragma unroll
        for (int k = 0; k < 12; k++) mg[k] = mp[k];
        return;
    }
    if (gu >= 0) {
        const float* m = Mp + 12 * gu;
        float a = m[0]*pu0 + m[1]*pu1 + m[2]*pu2 + m[9];
        float b = m[3]*pu0 + m[4]*pu1 + m[5]*pu2 + m[10];
        float e = m[6]*pu0 + m[7]*pu1 + m[8]*pu2 + m[11];
        pu0 = a; pu1 = b; pu2 = e;
    }
    if (gv >= 0) {
        const float* m = Mp + 12 * gv;
        float a = m[0]*pv0 + m[1]*pv1 + m[2]*pv2 + m[9];
        float b = m[3]*pv0 + m[4]*pv1 + m[5]*pv2 + m[10];
        float e = m[6]*pv0 + m[7]*pv1 + m[8]*pv2 + m[11];
        pv0 = a; pv1 = b; pv2 = e;
    }
    float ax = pv0-pu0, ay = pv1-pu1, az = pv2-pu2;
    float inv = 1.0f / (sqrtf(ax*ax + ay*ay + az*az) + 1e-12f);
    ax *= inv; ay *= inv; az *= inv;
    float t = 1.0f - c;
    float R00 = c + t*ax*ax,     R01 = -s*az + t*ax*ay, R02 =  s*ay + t*ax*az;
    float R10 =  s*az + t*ay*ax, R11 = c + t*ay*ay,     R12 = -s*ax + t*ay*az;
    float R20 = -s*ay + t*az*ax, R21 =  s*ax + t*az*ay, R22 = c + t*az*az;
    const float* mp = Mp + 12 * g;
    mg[0] = R00*mp[0] + R01*mp[3] + R02*mp[6];
    mg[1] = R00*mp[1] + R01*mp[4] + R02*mp[7];
    mg[2] = R00*mp[2] + R01*mp[5] + R02*mp[8];
    mg[3] = R10*mp[0] + R11*mp[3] + R12*mp[6];
    mg[4] = R10*mp[1] + R11*mp[4] + R12*mp[7];
    mg[5] = R10*mp[2] + R11*mp[5] + R12*mp[8];
    mg[6] = R20*mp[0] + R21*mp[3] + R22*mp[6];
    mg[7] = R20*mp[1] + R21*mp[4] + R22*mp[7];
    mg[8] = R20*mp[2] + R21*mp[5] + R22*mp[8];
    float d0 = mp[9]-pv0, d1 = mp[10]-pv1, d2 = mp[11]-pv2;
    mg[9]  = R00*d0 + R01*d1 + R02*d2 + pv0;
    mg[10] = R10*d0 + R11*d1 + R12*d2 + pv1;
    mg[11] = R20*d0 + R21*d1 + R22*d2 + pv2;
}

// apply4_k (Path A): thread t handles nodes 4t..4t+3 via 3x float4 loads and
// stores. 4 | K_TWIST(40) and 4 | N_PER_DOM(100) -> all 4 nodes share one
// Mf group (t/10) and one rt domain (t/25); no straddle.
__global__ __launch_bounds__(256) void apply4_k(const float* __restrict__ pos,
                                                const float* __restrict__ Mf,
                                                const float* __restrict__ rt,
                                                float* __restrict__ out)
{
    int t = blockIdx.x * 256 + threadIdx.x;
    if (t >= N_NODE / 4) return;
    const float* w = rt + 12 * (t / 25);
    const float4* pp = ((const float4*)pos) + (size_t)3 * t;
    float4 A = pp[0], B = pp[1], C = pp[2];
    float q[4][3] = { {A.x, A.y, A.z}, {A.w, B.x, B.y},
                      {B.z, B.w, C.x}, {C.y, C.z, C.w} };
    float r[4][3];
    if (t < N_TWIST / 4) {
        const float* m = Mf + 12 * (t / 10);
        #pragma unroll
        for (int j = 0; j < 4; j++) {
            float p0 = m[0]*q[j][0] + m[1]*q[j][1] + m[2]*q[j][2] + m[9];
            float p1 = m[3]*q[j][0] + m[4]*q[j][1] + m[5]*q[j][2] + m[10];
            float p2 = m[6]*q[j][0] + m[7]*q[j][1] + m[8]*q[j][2] + m[11];
            r[j][0] = w[0]*p0 + w[1]*p1 + w[2]*p2 + w[9];
            r[j][1] = w[3]*p0 + w[4]*p1 + w[5]*p2 + w[10];
            r[j][2] = w[6]*p0 + w[7]*p1 + w[8]*p2 + w[11];
        }
    } else {
        #pragma unroll
        for (int j = 0; j < 4; j++) {
            r[j][0] = w[0]*q[j][0] + w[1]*q[j][1] + w[2]*q[j][2] + w[9];
            r[j][1] = w[3]*q[j][0] + w[4]*q[j][1] + w[5]*q[j][2] + w[10];
            r[j][2] = w[6]*q[j][0] + w[7]*q[j][1] + w[8]*q[j][2] + w[11];
        }
    }
    float4* op = ((float4*)out) + (size_t)3 * t;
    op[0] = make_float4(r[0][0], r[0][1], r[0][2], r[1][0]);
    op[1] = make_float4(r[1][1], r[1][2], r[2][0], r[2][1]);
    op[2] = make_float4(r[2][2], r[3][0], r[3][1], r[3][2]);
}

// ===========================================================================
// Path B kernels — proven baseline structure (scratch in out-high)
// ===========================================================================

__global__ __launch_bounds__(256) void compose_legacy_k(
    const float* __restrict__ pos, const float* __restrict__ info_level,
    const int* __restrict__ anno, const float* __restrict__ eps,
    const float* __restrict__ uni, const int* __restrict__ from_prior_p,
    const float* __restrict__ Mp, float* __restrict__ Mc, int o)
{
    int g = blockIdx.x * 256 + threadIdx.x;
    if (g >= N_GROUP) return;
    int b = g * MAX_ORDER + o;
    float* mg = Mc + 12 * g;
    if (anno[3*b] != o) {                       // safety fallback
        if (o == 0) {
            mg[0]=1.f; mg[1]=0.f; mg[2]=0.f;
            mg[3]=0.f; mg[4]=1.f; mg[5]=0.f;
            mg[6]=0.f; mg[7]=0.f; mg[8]=1.f;
            mg[9]=0.f; mg[10]=0.f; mg[11]=0.f;
        } else {
            const float* mp = Mp + 12 * g;
            #pragma unroll
            for (int k = 0; k < 12; k++) mg[k] = mp[k];
        }
        return;
    }
    int u = anno[3*b + 1];
    int v = anno[3*b + 2];
    float pu0 = pos[3*u+0], pu1 = pos[3*u+1], pu2 = pos[3*u+2];
    float pv0 = pos[3*v+0], pv1 = pos[3*v+1], pv2 = pos[3*v+2];
    if (o > 0) {
        if (u < N_TWIST) {
            const float* m = Mp + 12 * (u / K_TWIST);
            float a = m[0]*pu0 + m[1]*pu1 + m[2]*pu2 + m[9];
            float c = m[3]*pu0 + m[4]*pu1 + m[5]*pu2 + m[10];
            float e = m[6]*pu0 + m[7]*pu1 + m[8]*pu2 + m[11];
            pu0 = a; pu1 = c; pu2 = e;
        }
        if (v < N_TWIST) {
            const float* m = Mp + 12 * (v / K_TWIST);
            float a = m[0]*pv0 + m[1]*pv1 + m[2]*pv2 + m[9];
            float c = m[3]*pv0 + m[4]*pv1 + m[5]*pv2 + m[10];
            float e = m[6]*pv0 + m[7]*pv1 + m[8]*pv2 + m[11];
            pv0 = a; pv1 = c; pv2 = e;
        }
    }
    float info = info_level[b];
    float ang  = eps[b] * (1.0f - info) * SIGMA_MAXF;
    if (from_prior_p[0] != 0 && info == 0.0f) ang = uni[b];
    float ax = pv0-pu0, ay = pv1-pu1, az = pv2-pu2;
    float inv = 1.0f / (sqrtf(ax*ax + ay*ay + az*az) + 1e-12f);
    ax *= inv; ay *= inv; az *= inv;
    float c = cosf(ang), s = sinf(ang), t = 1.0f - c;
    float R00 = c + t*ax*ax,     R01 = -s*az + t*ax*ay, R02 =  s*ay + t*ax*az;
    float R10 =  s*az + t*ay*ax, R11 = c + t*ay*ay,     R12 = -s*ax + t*ay*az;
    float R20 = -s*ay + t*az*ax, R21 =  s*ax + t*az*ay, R22 = c + t*az*az;
    if (o == 0) {
        mg[0]=R00; mg[1]=R01; mg[2]=R02;
        mg[3]=R10; mg[4]=R11; mg[5]=R12;
        mg[6]=R20; mg[7]=R21; mg[8]=R22;
        mg[9]  = pv0 - (R00*pv0 + R01*pv1 + R02*pv2);
        mg[10] = pv1 - (R10*pv0 + R11*pv1 + R12*pv2);
        mg[11] = pv2 - (R20*pv0 + R21*pv1 + R22*pv2);
    } else {
        const float* mp = Mp + 12 * g;
        mg[0] = R00*mp[0] + R01*mp[3] + R02*mp[6];
        mg[1] = R00*mp[1] + R01*mp[4] + R02*mp[7];
        mg[2] = R00*mp[2] + R01*mp[5] + R02*mp[8];
        mg[3] = R10*mp[0] + R11*mp[3] + R12*mp[6];
        mg[4] = R10*mp[1] + R11*mp[4] + R12*mp[7];
        mg[5] = R10*mp[2] + R11*mp[5] + R12*mp[8];
        mg[6] = R20*mp[0] + R21*mp[3] + R22*mp[6];
        mg[7] = R20*mp[1] + R21*mp[4] + R22*mp[7];
        mg[8] = R20*mp[2] + R21*mp[5] + R22*mp[8];
        float d0 = mp[9]-pv0, d1 = mp[10]-pv1, d2 = mp[11]-pv2;
        mg[9]  = R00*d0 + R01*d1 + R02*d2 + pv0;
        mg[10] = R10*d0 + R11*d1 + R12*d2 + pv1;
        mg[11] = R20*d0 + R21*d1 + R22*d2 + pv2;
    }
}

__global__ void apply_low_k(const float* __restrict__ pos,
                            const float* __restrict__ Mf,
                            const float* __restrict__ rt,
                            float* __restrict__ out)
{
    int n = blockIdx.x * 256 + threadIdx.x;
    if (n >= N_TWIST) return;
    const float* m = Mf + 12 * (n / K_TWIST);
    const float* w = rt + 12 * (n / N_PER_DOM);
    float q0 = pos[3*n+0], q1 = pos[3*n+1], q2 = pos[3*n+2];
    float p0 = m[0]*q0 + m[1]*q1 + m[2]*q2 + m[9];
    float p1 = m[3]*q0 + m[4]*q1 + m[5]*q2 + m[10];
    float p2 = m[6]*q0 + m[7]*q1 + m[8]*q2 + m[11];
    out[3*n+0] = w[0]*p0 + w[1]*p1 + w[2]*p2 + w[9];
    out[3*n+1] = w[3]*p0 + w[4]*p1 + w[5]*p2 + w[10];
    out[3*n+2] = w[6]*p0 + w[7]*p1 + w[8]*p2 + w[11];
}

__global__ void apply_high_k(const float* __restrict__ pos,
                             const float* __restrict__ rt,
                             float* __restrict__ out)
{
    int i = blockIdx.x * 256 + threadIdx.x;
    int n = N_TWIST + i;
    if (n >= N_NODE) return;
    const float* w = rt + 12 * (n / N_PER_DOM);
    float q0 = pos[3*n+0], q1 = pos[3*n+1], q2 = pos[3*n+2];
    out[3*n+0] = w[0]*q0 + w[1]*q1 + w[2]*q2 + w[9];
    out[3*n+1] = w[3]*q0 + w[4]*q1 + w[5]*q2 + w[10];
    out[3*n+2] = w[6]*q0 + w[7]*q1 + w[8]*q2 + w[11];
}

// ===========================================================================
// Shared kernels (both paths)
// ===========================================================================

__global__ __launch_bounds__(256) void reduce_k(const float* __restrict__ pos,
                                                const float* __restrict__ Mf,
                                                float* __restrict__ sums)
{
    int wave = threadIdx.x >> 6;
    int lane = threadIdx.x & 63;
    int d = blockIdx.x * 4 + wave;          // grid = 2500 -> d in [0,10000)
    float a[15];
    #pragma unroll
    for (int k = 0; k < 15; k++) a[k] = 0.f;
    for (int i = lane; i < N_PER_DOM; i += 64) {
        int n = d * N_PER_DOM + i;
        float q0 = pos[3*n+0], q1 = pos[3*n+1], q2 = pos[3*n+2];
        float p0 = q0, p1 = q1, p2 = q2;
        if (n < N_TWIST) {
            const float* m = Mf + 12 * (n / K_TWIST);
            p0 = m[0]*q0 + m[1]*q1 + m[2]*q2 + m[9];
            p1 = m[3]*q0 + m[4]*q1 + m[5]*q2 + m[10];
            p2 = m[6]*q0 + m[7]*q1 + m[8]*q2 + m[11];
        }
        a[0]+=p0;    a[1]+=p1;    a[2]+=p2;
        a[3]+=q0;    a[4]+=q1;    a[5]+=q2;
        a[6]+=p0*q0; a[7]+=p0*q1; a[8]+=p0*q2;
        a[9]+=p1*q0; a[10]+=p1*q1;a[11]+=p1*q2;
        a[12]+=p2*q0;a[13]+=p2*q1;a[14]+=p2*q2;
    }
    #pragma unroll
    for (int off = 32; off > 0; off >>= 1)
        #pragma unroll
        for (int k = 0; k < 15; k++) a[k] += __shfl_down(a[k], off);
    if (lane == 0) {
        float* sd = sums + (size_t)d * 15;
        #pragma unroll
        for (int k = 0; k < 15; k++) sd[k] = a[k];
    }
}

__device__ inline void cross3d(const double a[3], const double b[3], double r[3])
{
    r[0] = a[1]*b[2] - a[2]*b[1];
    r[1] = a[2]*b[0] - a[0]*b[2];
    r[2] = a[0]*b[1] - a[1]*b[0];
}

__device__ void kabsch_from_sums(const float* s, float* __restrict__ rt)
{
    const double inv_n = 1.0 / (double)N_PER_DOM;
    double sP[3] = { s[0], s[1], s[2] };
    double sQ[3] = { s[3], s[4], s[5] };
    double H[3][3];
    #pragma unroll
    for (int i = 0; i < 3; i++)
        #pragma unroll
        for (int j = 0; j < 3; j++)
            H[i][j] = (double)s[6 + 3*i + j] - sP[i]*sQ[j]*inv_n;
    double A[3][3];
    #pragma unroll
    for (int i = 0; i < 3; i++)
        #pragma unroll
        for (int j = 0; j < 3; j++)
            A[i][j] = H[0][i]*H[0][j] + H[1][i]*H[1][j] + H[2][i]*H[2][j];
    double V[3][3] = {{1,0,0},{0,1,0},{0,0,1}};
    for (int sweep = 0; sweep < 30; sweep++) {
        double off = A[0][1]*A[0][1] + A[0][2]*A[0][2] + A[1][2]*A[1][2];
        double n2  = A[0][0]*A[0][0] + A[1][1]*A[1][1] + A[2][2]*A[2][2];
        if (off <= 1e-28 * n2) break;
        for (int pp = 0; pp < 3; pp++) {
            int p = (pp == 2) ? 1 : 0;
            int q = (pp == 0) ? 1 : 2;
            double apq = A[p][q];
            if (apq == 0.0) continue;
            double tau = (A[q][q] - A[p][p]) / (2.0 * apq);
            double tj  = (tau >= 0.0 ? 1.0 : -1.0) / (fabs(tau) + sqrt(1.0 + tau*tau));
            double cj  = 1.0 / sqrt(1.0 + tj*tj);
            double sj  = tj * cj;
            int r = 3 - p - q;
            double app = A[p][p], aqq = A[q][q];
            A[p][p] = app - tj*apq;
            A[q][q] = aqq + tj*apq;
            A[p][q] = 0.0; A[q][p] = 0.0;
            double arp = A[r][p], arq = A[r][q];
            A[r][p] = cj*arp - sj*arq; A[p][r] = A[r][p];
            A[r][q] = sj*arp + cj*arq; A[q][r] = A[r][q];
            #pragma unroll
            for (int k = 0; k < 3; k++) {
                double vp = V[k][p], vq = V[k][q];
                V[k][p] = cj*vp - sj*vq;
                V[k][q] = sj*vp + cj*vq;
            }
        }
    }
    double wv[3] = { A[0][0], A[1][1], A[2][2] };
    int i0 = 0, i1 = 1, i2 = 2;
    if (wv[i0] < wv[i1]) { int t = i0; i0 = i1; i1 = t; }
    if (wv[i0] < wv[i2]) { int t = i0; i0 = i2; i2 = t; }
    if (wv[i1] < wv[i2]) { int t = i1; i1 = i2; i2 = t; }
    double v0[3] = { V[0][i0], V[1][i0], V[2][i0] };
    double v1[3] = { V[0][i1], V[1][i1], V[2][i1] };
    double v2[3] = { V[0][i2], V[1][i2], V[2][i2] };
    double s0 = sqrt(fmax(wv[i0], 0.0));
    double Rg[3][3];
    if (s0 < 1e-200) {
        Rg[0][0]=1; Rg[0][1]=0; Rg[0][2]=0;
        Rg[1][0]=0; Rg[1][1]=1; Rg[1][2]=0;
        Rg[2][0]=0; Rg[2][1]=0; Rg[2][2]=1;
    } else {
        double u0[3], u1[3], u2[3];
        #pragma unroll
        for (int i = 0; i < 3; i++)
            u0[i] = H[i][0]*v0[0] + H[i][1]*v0[1] + H[i][2]*v0[2];
        double n0 = sqrt(u0[0]*u0[0] + u0[1]*u0[1] + u0[2]*u0[2]);
        if (n0 > 0.0) { u0[0]/=n0; u0[1]/=n0; u0[2]/=n0; }
        else { u0[0]=1; u0[1]=0; u0[2]=0; }
        #pragma unroll
        for (int i = 0; i < 3; i++)
            u1[i] = H[i][0]*v1[0] + H[i][1]*v1[1] + H[i][2]*v1[2];
        double dp = u0[0]*u1[0] + u0[1]*u1[1] + u0[2]*u1[2];
        u1[0] -= dp*u0[0]; u1[1] -= dp*u0[1]; u1[2] -= dp*u0[2];
        double n1 = sqrt(u1[0]*u1[0] + u1[1]*u1[1] + u1[2]*u1[2]);
        if (n1 > 1e-12 * n0) { u1[0]/=n1; u1[1]/=n1; u1[2]/=n1; }
        else {
            double tv[3] = { (fabs(u0[0]) < 0.9) ? 1.0 : 0.0,
                             (fabs(u0[0]) < 0.9) ? 0.0 : 1.0, 0.0 };
            cross3d(u0, tv, u1);
            double nn = sqrt(u1[0]*u1[0] + u1[1]*u1[1] + u1[2]*u1[2]);
            u1[0]/=nn; u1[1]/=nn; u1[2]/=nn;
        }
        cross3d(u0, u1, u2);                    // det(U) = +1
        double c12[3]; cross3d(v1, v2, c12);
        double detV = v0[0]*c12[0] + v0[1]*c12[1] + v0[2]*c12[2];
        double dsg = (detV >= 0.0) ? 1.0 : -1.0;
        #pragma unroll
        for (int r = 0; r < 3; r++)
            #pragma unroll
            for (int c = 0; c < 3; c++)
                Rg[r][c] = v0[r]*u0[c] + v1[r]*u1[c] + dsg*v2[r]*u2[c];
    }
    double cP[3] = { sP[0]*inv_n, sP[1]*inv_n, sP[2]*inv_n };
    double cQ[3] = { sQ[0]*inv_n, sQ[1]*inv_n, sQ[2]*inv_n };
    #pragma unroll
    for (int i = 0; i < 3; i++) {
        rt[3*i+0] = (float)Rg[i][0];
        rt[3*i+1] = (float)Rg[i][1];
        rt[3*i+2] = (float)Rg[i][2];
        rt[9+i] = (float)(cQ[i] - (Rg[i][0]*cP[0] + Rg[i][1]*cP[1] + Rg[i][2]*cP[2]));
    }
}

__global__ __launch_bounds__(128) void svd_k(const float* __restrict__ sums,
                                             float* __restrict__ rt)
{
    int d = blockIdx.x * 128 + threadIdx.x;
    if (d >= N_DOMAIN) return;
    kabsch_from_sums(sums + (size_t)d * 15, rt + (size_t)d * 12);
}

// ---------------------------------------------------------------------------
extern "C" void kernel_launch(void* const* d_in, const int* in_sizes, int n_in,
                              void* d_out, int out_size, void* d_ws, size_t ws_size,
                              hipStream_t stream)
{
    const float* pos        = (const float*)d_in[0];
    const float* info_level = (const float*)d_in[1];
    const int*   anno       = (const int*)  d_in[2];
    const float* eps        = (const float*)d_in[6];
    const float* uni        = (const float*)d_in[7];
    const int*   from_prior = (const int*)  d_in[8];
    float* out = (float*)d_out;
    float* ws  = (float*)d_ws;

    if (ws_size >= (size_t)WS_FLOATS_NEEDED * sizeof(float)) {
        // ---------------- Path A: 11 dispatches ----------------
        float* rt   = ws + WS_RT;
        float* M0   = ws + WS_M0;
        float* M1   = ws + WS_M1;
        float* sums = ws + WS_SUMS;
        float* prep = ws + WS_PREP;

        // Fused: compose o=0 (independent of prep) + prep for o=1..7.
        fused_prep_c0_k<<<FUSED_BLOCKS, 256, 0, stream>>>(
            pos, info_level, anno, eps, uni, from_prior, prep, M0);

        // 7 slim compose dispatches; boundary = device-wide barrier.
        // Ping-pong: o=0 wrote M0; o odd -> M1, o even -> M0; o=7 -> M1.
        for (int o = 1; o < MAX_ORDER; o++) {
            const float* Mp = (o & 1) ? M0 : M1;
            float*       Mc = (o & 1) ? M1 : M0;
            compose_k<<<(N_GROUP + 255)/256, 256, 0, stream>>>(prep, Mp, Mc, o);
        }
        float* Mf = M1;

        reduce_k<<<N_DOMAIN / 4, 256, 0, stream>>>(pos, Mf, sums);
        svd_k<<<(N_DOMAIN + 127)/128, 128, 0, stream>>>(sums, rt);
        apply4_k<<<(N_NODE/4 + 255)/256, 256, 0, stream>>>(pos, Mf, rt, out);
    } else {
        // ---------------- Path B: proven layout (scratch in out-high) ------
        float* rt   = ws;                                 // 480 KB proven safe
        float* M0   = out + (size_t)3 * N_TWIST;          // 150,000 floats
        float* M1   = M0 + 12 * N_GROUP;                  // 150,000 floats
        float* sums = M1 + 12 * N_GROUP;                  // 150,000 floats

        for (int o = 0; o < MAX_ORDER; o++) {
            const float* Mp = (o & 1) ? M0 : M1;
            float*       Mc = (o & 1) ? M1 : M0;
            compose_legacy_k<<<(N_GROUP + 255)/256, 256, 0, stream>>>(
                pos, info_level, anno, eps, uni, from_prior, Mp, Mc, o);
        }
        float* Mf = M1;

        reduce_k<<<N_DOMAIN / 4, 256, 0, stream>>>(pos, Mf, sums);
        svd_k<<<(N_DOMAIN + 127)/128, 128, 0, stream>>>(sums, rt);
        apply_low_k<<<(N_TWIST + 255)/256, 256, 0, stream>>>(pos, Mf, rt, out);
        apply_high_k<<<(N_NODE - N_TWIST + 255)/256, 256, 0, stream>>>(pos, rt, out);
    }
}